// Round 1
// 109.478 us; speedup vs baseline: 1.0351x; 1.0351x over previous
//
#include <hip/hip_runtime.h>
#include <hip/hip_fp16.h>

// DFMB PSROIAlign — separable (rank-1) weights + phase-split sides + fp16
// packed gather source.
//
// R7 lesson: perf is pinned by the vector-memory addresser/L1 line path —
// every gather's 64 lanes touch ~64 distinct 64B lines (pixel==line, no
// intra-wave sharing), so cost ~ #loads x lines, independent of occupancy.
// R8 packed 10 channels into 20B fp16 -> 18 loads/bin (b128+b32 per pixel).
//
// R9: kill the 9 per-pixel b32s (ch8,9). Split storage:
//   ftA: 16B/pixel = ch0-7 (4x half2)           -> 9 x b128 per bin (as before)
//   ftB: 4B/pixel  = ch8,9 (1x half2), stored as FOUR phase-shifted copies:
//        copy m holds pixel (i+m) at element i. A patch ROW (3 consecutive
//        pixels, 12B) is covered by ONE 16B-ALIGNED b128 from copy
//        m = flatpix&3 at element flatpix&~3 (NPIX%4==0 -> always aligned,
//        aligned-down start never overruns a copy). Right-edge clip handled
//        by a 2-deep cndmask select (index min(q, 33-X0), static).
// Loads/bin: 18 -> 12 (-33% gather instructions & line-touches).
// ws need unchanged: 906,304 (ftA) + 4*226,576 (ftB copies) = 1,812,608 B.

#define NC 10
#define NBIN 49
#define FH 34
#define FW 34
#define PLANE (FH * FW)
#define NPIX (NBIN * PLANE)  // 56644, %4 == 0 (alignment of ftB copies)
#define RPB 16               // rois per block
#define TSTRIDE 491          // out-tile row stride (odd -> conflict-free flush)
#define NSIDE 14

__global__ __launch_bounds__(256) void prep_kernel(
    const float* __restrict__ ft, unsigned int* __restrict__ ws)
{
    const int p = blockIdx.x * 256 + threadIdx.x;  // over 49*1156 pixels
    if (p >= NPIX) return;
    unsigned int h2[5];
#pragma unroll
    for (int c = 0; c < 5; ++c) {
        const __half lo = __float2half_rn(ft[(2 * c)     * NPIX + p]);
        const __half hi = __float2half_rn(ft[(2 * c + 1) * NPIX + p]);
        const __half2 hh = __halves2half2(lo, hi);
        h2[c] = *(const unsigned int*)&hh;
    }
    // ftA: ch0-7, 16B/pixel
    *(uint4*)(ws + (size_t)p * 4) = make_uint4(h2[0], h2[1], h2[2], h2[3]);
    // ftB: ch8-9, 4 phase-shifted copies; copy m, element i <- pixel i+m
    unsigned int* fb = ws + (size_t)NPIX * 4;
#pragma unroll
    for (int m = 0; m < 4; ++m)
        if (p >= m) fb[(size_t)m * NPIX + (p - m)] = h2[4];
}

__device__ __forceinline__ void fma2(float w, unsigned int u, float& s0, float& s1)
{
    const __half2 h = *(const __half2*)&u;
    s0 = fmaf(w, __half2float(__low2half(h)),  s0);   // -> v_fma_mix_f32
    s1 = fmaf(w, __half2float(__high2half(h)), s1);
}

__global__ __launch_bounds__(256) void main_kernel(
    const float* __restrict__ rois, const unsigned int* __restrict__ ftH,
    const float* __restrict__ ft, float* __restrict__ out, int N, int use_t)
{
    __shared__ float sides[NSIDE][RPB][8];  // 7 KB
    __shared__ float tile[RPB][TSTRIDE];    // 31.4 KB

    const int r = threadIdx.x & (RPB - 1);  // roi within block
    const int s = threadIdx.x >> 4;         // slot 0..15
    const int n = blockIdx.x * RPB + r;
    const bool valid = (n < N);

    float rsw = 0.f, rsh = 0.f, rew = 0.f, reh = 0.f;
    if (valid) {
        rsw = rois[n * 5 + 1] * 0.125f;  // /STRIDE(8), exact pow2
        rsh = rois[n * 5 + 2] * 0.125f;
        rew = rois[n * 5 + 3] * 0.125f;
        reh = rois[n * 5 + 4] * 0.125f;
    }
    // Explicit _rn chain: floor/ceil/compare inputs must bit-match numpy fp32.
    float rheight = __fsub_rn(reh, rsh);
    if (!(rheight > 0.1f)) rheight = 0.1f;
    float rwidth = __fsub_rn(rew, rsw);
    if (!(rwidth > 0.1f)) rwidth = 0.1f;
    const float bsh   = __fdiv_rn(rheight, 7.0f);
    const float bsw   = __fdiv_rn(rwidth, 7.0f);
    const float sub_h = __fdiv_rn(bsh, 4.0f);
    const float sub_w = __fdiv_rn(bsw, 4.0f);

    // ---- phase 1: one axis-side per slot (slots 0..13 active) ----
    if (s < NSIDE) {
        const bool isY = (s < 7);
        const int  k   = isY ? s : s - 7;
        const float st = isY ? rsh : rsw;
        const float bs = isY ? bsh : bsw;
        const float sb = isY ? sub_h : sub_w;
        const float start = floorf(__fadd_rn(st, __fmul_rn((float)k, bs)));

        float A[3] = {0.f, 0.f, 0.f}, B[3] = {0.f, 0.f, 0.f};
        float cnt = 0.f;
        int P0 = 0;
#pragma unroll
        for (int i = 0; i < 4; ++i) {
            const float h = __fadd_rn(start, __fmul_rn((float)i + 0.5f, sb));
            const bool ok = (h > -1.0f) && (h < 34.0f);
            const int p1 = (int)floorf(h);
            const int p2 = (int)ceilf(h);
            const bool v1 = (p1 >= 0) && (p1 < 34);
            const bool v2 = (p2 >= 0) && (p2 < 34);
            const int p1c = min(max(p1, 0), 33);
            const int p2c = min(max(p2, 0), 33);
            const float d = __fsub_rn(h, (float)p1c);  // vs CLIPPED corner
            if (i == 0) P0 = p1c;                      // min (h increasing)
            const int i1 = p1c - P0, i2 = p2c - P0;    // in {0,1,2}
            const float t1 = ok ? (1.0f - d) : 0.0f;
            const float t2 = ok ? d : 0.0f;
            // bad11 = (!x1v || !x2v) && (y1v || y2v): X carries "invalid",
            // Y carries "valid".
            const bool bsel = isY ? (v1 || v2) : ((!v1) || (!v2));
            const float tb = (ok && bsel) ? (1.0f - d) : 0.0f;
            cnt += ok ? 1.0f : 0.0f;
#pragma unroll
            for (int p = 0; p < 3; ++p) {
                A[p] += (i1 == p) ? t1 : 0.0f;
                A[p] += (i2 == p) ? t2 : 0.0f;
                B[p] += (i1 == p) ? tb : 0.0f;
            }
        }
        float* sp = &sides[s][r][0];
        sp[0] = A[0]; sp[1] = A[1]; sp[2] = A[2];
        sp[3] = B[0]; sp[4] = B[1]; sp[5] = B[2];
        sp[6] = cnt;  sp[7] = (float)P0;
    }
    __syncthreads();

    // ---- phase 2: 4 bins/thread; 12 gathers/bin (9 ftA b128 + 3 ftB rows) ----
#pragma unroll
    for (int j = 0; j < 4; ++j) {
        const int bin = j * RPB + s;
        if (valid && bin < NBIN) {
            const int ph = bin / 7;
            const int pw = bin - ph * 7;

            const float4 ya = *(const float4*)&sides[ph][r][0];
            const float4 yb = *(const float4*)&sides[ph][r][4];
            const float4 xa = *(const float4*)&sides[7 + pw][r][0];
            const float4 xb = *(const float4*)&sides[7 + pw][r][4];
            const float AY[3] = {ya.x, ya.y, ya.z};
            const float BY[3] = {ya.w, yb.x, yb.y};
            const float cntY  = yb.z;
            const int   Y0    = (int)yb.w;
            const float AX[3] = {xa.x, xa.y, xa.z};
            const float BX[3] = {xa.w, xb.x, xb.y};
            const float cntX  = xb.z;
            const int   X0    = (int)xb.w;

            const int binbase = bin * PLANE;
            const int rowo[3] = {binbase + Y0 * FW,
                                 binbase + min(Y0 + 1, FH - 1) * FW,
                                 binbase + min(Y0 + 2, FH - 1) * FW};
            const int colo[3] = {X0, min(X0 + 1, FW - 1), min(X0 + 2, FW - 1)};

            float wgt[9];
            int   off[9];
#pragma unroll
            for (int p = 0; p < 3; ++p)
#pragma unroll
                for (int q = 0; q < 3; ++q) {
                    const float w = AY[p] * AX[q] - BY[p] * BX[q];
                    wgt[3 * p + q] = w;
                    // zero-weight -> shared dummy pixel (plane origin): loads
                    // stay batched, masked lanes share one hot line.
                    off[3 * p + q] = (w != 0.0f) ? (rowo[p] + colo[q]) : binbase;
                }

            float sum[NC];
#pragma unroll
            for (int c = 0; c < NC; ++c) sum[c] = 0.f;

            if (use_t) {
                const unsigned int* fB = ftH + (size_t)NPIX * 4;
                // ch8,9: one aligned b128 per patch row from phase copy
                unsigned int rb[3][4];
#pragma unroll
                for (int p = 0; p < 3; ++p) {
                    const bool rnz = (wgt[3 * p]     != 0.0f) ||
                                     (wgt[3 * p + 1] != 0.0f) ||
                                     (wgt[3 * p + 2] != 0.0f);
                    const int fp = rnz ? (rowo[p] + X0) : binbase;
                    const int m  = fp & 3;
                    const int i0 = fp & ~3;
                    const uint4 V = *(const uint4*)(fB + (size_t)m * NPIX + i0);
                    rb[p][0] = V.x; rb[p][1] = V.y; rb[p][2] = V.z; rb[p][3] = V.w;
                }
                // ch0-7: 9 per-pixel b128 from ftA
#pragma unroll
                for (int k = 0; k < 9; ++k) {
                    const uint4 A = *(const uint4*)(ftH + (size_t)off[k] * 4);
                    const float w = wgt[k];
                    fma2(w, A.x, sum[0], sum[1]);
                    fma2(w, A.y, sum[2], sum[3]);
                    fma2(w, A.z, sum[4], sum[5]);
                    fma2(w, A.w, sum[6], sum[7]);
                }
                // ch8,9: select column within row vector (right-edge clip:
                // element index = min(q, 33-X0), static cndmask tree)
                const int e = (FW - 1) - X0;  // >= 0
#pragma unroll
                for (int p = 0; p < 3; ++p) {
                    const unsigned int u0 = rb[p][0];
                    const unsigned int u1 = (e >= 1) ? rb[p][1] : rb[p][0];
                    const unsigned int u2 = (e >= 2) ? rb[p][2] : u1;
                    fma2(wgt[3 * p + 0], u0, sum[8], sum[9]);
                    fma2(wgt[3 * p + 1], u1, sum[8], sum[9]);
                    fma2(wgt[3 * p + 2], u2, sum[8], sum[9]);
                }
            } else {
#pragma unroll
                for (int k = 0; k < 9; ++k) {
                    const float w = wgt[k];
#pragma unroll
                    for (int c = 0; c < NC; ++c)
                        sum[c] = fmaf(w, ft[c * NPIX + off[k]], sum[c]);
                }
            }

            const float cnt = cntY * cntX;
            const float inv = (cnt > 0.0f) ? __fdiv_rn(1.0f, cnt) : 1.0f;
            float* tp = &tile[r][0];
#pragma unroll
            for (int c = 0; c < NC; ++c) tp[c * NBIN + bin] = sum[c] * inv;
        }
    }

    __syncthreads();

    // Coalesced flush: 16 rois x 490 contiguous floats each.
    const int n0 = blockIdx.x * RPB;
    for (int i = threadIdx.x; i < RPB * (NC * NBIN); i += 256) {
        const int row = i / (NC * NBIN);
        const int col = i - row * (NC * NBIN);
        const int n2 = n0 + row;
        if (n2 < N) out[(size_t)n2 * (NC * NBIN) + col] = tile[row][col];
    }
}

extern "C" void kernel_launch(void* const* d_in, const int* in_sizes, int n_in,
                              void* d_out, int out_size, void* d_ws, size_t ws_size,
                              hipStream_t stream) {
    const float* ft   = (const float*)d_in[0];
    const float* rois = (const float*)d_in[1];
    float* out        = (float*)d_out;
    const int N = in_sizes[1] / 5;

    // ftA (16B/pixel) + 4 ftB copies (4B/pixel each) = 1,812,608 B
    const size_t need = (size_t)NPIX * 16 + (size_t)4 * NPIX * 4;
    const int use_t = (ws_size >= need) ? 1 : 0;
    unsigned int* ftH = (unsigned int*)d_ws;

    if (use_t) {
        prep_kernel<<<(NPIX + 255) / 256, 256, 0, stream>>>(ft, ftH);
    }
    main_kernel<<<(N + RPB - 1) / RPB, 256, 0, stream>>>(rois, ftH, ft, out, N, use_t);
}